// Round 6
// baseline (248.412 us; speedup 1.0000x reference)
//
#include <hip/hip_runtime.h>

#define S_LEN 256
#define B_SZ  512
#define T_TAGS 128
#define TP2   130
#define PAD_I (-1)
#define RS    4

#define FWD_BLOCKS 32
#define NQ 32
#define QLEN 8
#define NUM_SUB 4
#define NUM_BLOCKS (NQ * NUM_SUB)
#define TOT_BLOCKS (FWD_BLOCKS + NUM_BLOCKS)
#define NTHR 192

typedef __bf16 bf16x8 __attribute__((ext_vector_type(8)));
typedef float  f32x4  __attribute__((ext_vector_type(4)));

// logical k-slot (c,lg,e) -> physical src-tag j. Chosen so D(C-layout) -> next B-fragment
// is same-lane: B slot (c,lg,e) = D[jt=2c+(e>>2)] reg r=(e&3) of the SAME lane.
#define PI_J(c, lg, e) ((2*(c) + ((e) >> 2))*16 + (lg)*4 + ((e) & 3))

// LDS-only barrier: leaves global loads in flight.
__device__ __forceinline__ void bar_lds() {
    asm volatile("s_waitcnt lgkmcnt(0)\n\ts_barrier" ::: "memory");
}

__device__ __forceinline__ void consumer_step(
    int s, const bf16x8 (&A)[8][4], bf16x8 (&Q)[4], float &M, int tgc,
    const float (&EE)[4][8][64][4], int l)
{
    // D[jt] = E^T x Q
    f32x4 d[8];
    const f32x4 z = {0.f, 0.f, 0.f, 0.f};
    #pragma unroll
    for (int jt = 0; jt < 8; ++jt) {
        d[jt] = __builtin_amdgcn_mfma_f32_16x16x32_bf16(A[jt][0], Q[0], z, 0, 0, 0);
        #pragma unroll
        for (int c = 1; c < 4; ++c)
            d[jt] = __builtin_amdgcn_mfma_f32_16x16x32_bf16(A[jt][c], Q[c], d[jt], 0, 0, 0);
    }
    // u = d * exp(em[s])
    float u[8][4];
    #pragma unroll
    for (int jt = 0; jt < 8; ++jt) {
        const f32x4 ee = *(const f32x4*)&EE[s & 3][jt][l][0];
        #pragma unroll
        for (int r = 0; r < 4; ++r) u[jt][r] = d[jt][r] * ee[r];
    }
    // amortized rescale every RS steps; invariant lp = M + log P
    float Mn = M;
    if ((s & (RS - 1)) == 0) {
        float R = u[0][0];
        #pragma unroll
        for (int jt = 0; jt < 8; ++jt)
            #pragma unroll
            for (int r = 0; r < 4; ++r) R = fmaxf(R, u[jt][r]);
        R = fmaxf(R, __shfl_xor(R, 16));
        R = fmaxf(R, __shfl_xor(R, 32));
        const float rr = 1.0f / R;
        Mn = M + __logf(R);
        #pragma unroll
        for (int jt = 0; jt < 8; ++jt)
            #pragma unroll
            for (int r = 0; r < 4; ++r) u[jt][r] *= rr;
    }
    // pack to next B-fragments (same-lane via PI_J)
    bf16x8 Qn[4];
    #pragma unroll
    for (int c = 0; c < 4; ++c)
        #pragma unroll
        for (int e = 0; e < 8; ++e)
            Qn[c][e] = (__bf16)u[2*c + (e >> 2)][e & 3];
    const bool live = (tgc != PAD_I);
    M = live ? Mn : M;
    #pragma unroll
    for (int c = 0; c < 4; ++c) Q[c] = live ? Qn[c] : Q[c];
}

__global__ __launch_bounds__(NTHR) void crf_main(
    const float* __restrict__ em,     // (S,B,T)
    const float* __restrict__ trans,  // (T+2,T+2)
    const int*   __restrict__ tags,   // (S,B)
    float* __restrict__ denom_out,    // (B)
    float* __restrict__ pl,           // (NQ,B)
    int*   __restrict__ pc,           // (NQ,B)
    unsigned int* __restrict__ counter,
    float* __restrict__ out)
{
    __shared__ __align__(16) float EE[4][8][64][4];   // exp(em) ring, 32 KB
    __shared__ int lastflag;
    const int t = threadIdx.x;

    if (blockIdx.x < FWD_BLOCKS) {
        const int w  = t >> 6;        // 0 = consumer, 1/2 = producers
        const int l  = t & 63;
        const int lm = l & 15;
        const int lg = l >> 4;
        const int b0 = blockIdx.x * 16;

        if (w == 0) {
            // ---- consumer ----
            bf16x8 A[8][4];
            #pragma unroll
            for (int jt = 0; jt < 8; ++jt)
                #pragma unroll
                for (int c = 0; c < 4; ++c)
                    #pragma unroll
                    for (int e = 0; e < 8; ++e)
                        A[jt][c][e] = (__bf16)__expf(trans[PI_J(c, lg, e)*TP2 + jt*16 + lm]);

            f32x4 em0[8];
            #pragma unroll
            for (int jt = 0; jt < 8; ++jt)
                em0[jt] = *(const f32x4*)&em[((size_t)0*B_SZ + b0 + lm)*T_TAGS + jt*16 + lg*4];
            bf16x8 Q[4];
            #pragma unroll
            for (int c = 0; c < 4; ++c)
                #pragma unroll
                for (int e = 0; e < 8; ++e) {
                    const int j  = PI_J(c, lg, e);
                    const int jt = 2*c + (e >> 2);
                    const int r  = e & 3;
                    Q[c][e] = (__bf16)__expf(trans[T_TAGS*TP2 + j] + em0[jt][r]);
                }
            float M = 0.f;
            int tg_cur = tags[1*B_SZ + b0 + lm];
            int tg_nxt = tags[2*B_SZ + b0 + lm];
            bar_lds();   // #0

            for (int s = 1; s <= S_LEN - 2; ++s) {
                const int sf = (s + 2 < S_LEN) ? s + 2 : S_LEN - 1;
                const int tg_fut = tags[sf*B_SZ + b0 + lm];
                consumer_step(s, A, Q, M, tg_cur, EE, l);
                tg_cur = tg_nxt; tg_nxt = tg_fut;
                bar_lds();
            }
            consumer_step(S_LEN - 1, A, Q, M, tg_cur, EE, l);

            // denom[b] = M + log(sum_j P[j]*exp(tend[j]))
            float sum = 0.f;
            #pragma unroll
            for (int c = 0; c < 4; ++c)
                #pragma unroll
                for (int e = 0; e < 8; ++e)
                    sum += (float)Q[c][e] * __expf(trans[PI_J(c, lg, e)*TP2 + (T_TAGS + 1)]);
            sum += __shfl_xor(sum, 16);
            sum += __shfl_xor(sum, 32);
            if (l < 16)
                denom_out[b0 + l] = M + __logf(sum);
        } else {
            // ---- producers: EE[(i+2)&3] = exp(em[i+2]); loads 2 intervals deep ----
            const int pj = (w - 1) * 4;
            auto LOADV = [&](f32x4 (&dst)[4], int s) {
                #pragma unroll
                for (int q = 0; q < 4; ++q)
                    dst[q] = *(const f32x4*)&em[((size_t)s*B_SZ + b0 + lm)*T_TAGS + (pj + q)*16 + lg*4];
            };
            auto EXPW = [&](int slot, const f32x4 (&src)[4]) {
                #pragma unroll
                for (int q = 0; q < 4; ++q) {
                    f32x4 v;
                    #pragma unroll
                    for (int r = 0; r < 4; ++r) v[r] = __expf(src[q][r]);
                    *(f32x4*)&EE[slot][pj + q][l][0] = v;
                }
            };
            f32x4 t0[4], t1[4], sA[4], sB[4];
            LOADV(t0, 1); LOADV(t1, 2);
            EXPW(1, t0);  EXPW(2, t1);
            LOADV(sB, 3); LOADV(sA, 4);
            bar_lds();   // #0

            for (int i = 1; i <= 253; i += 2) {
                EXPW((i + 2) & 3, sB);
                { const int s4 = (i + 4 < S_LEN) ? i + 4 : S_LEN - 1; LOADV(sB, s4); }
                bar_lds();
                EXPW((i + 3) & 3, sA);
                { const int s5 = (i + 5 < S_LEN) ? i + 5 : S_LEN - 1; LOADV(sA, s5); }
                bar_lds();
            }
            // consumer's last step needs no more EE / barriers
        }
    } else {
        // ---------------- numerator partials ----------------
        if (t < 128) {
            const int nb = blockIdx.x - FWD_BLOCKS;   // 0..127
            const int q  = nb >> 2;                   // s-chunk 0..31
            const int b  = (nb & 3) * 128 + t;
            const int s0 = q * QLEN;

            int tg[QLEN + 1];
            tg[0] = (s0 == 0) ? PAD_I : tags[(s0 - 1)*B_SZ + b];
            #pragma unroll
            for (int k = 0; k < QLEN; ++k)
                tg[k + 1] = tags[(s0 + k)*B_SZ + b];

            float acc = 0.f;
            int cnt = 0;
            if (q == 0) {
                const int t0  = tg[1];
                const int t0w = (t0 < 0) ? t0 + TP2 : t0;
                acc += trans[T_TAGS*TP2 + t0w];
            }
            #pragma unroll
            for (int k = 0; k < QLEN; ++k) {
                const int s = s0 + k;
                const int c = tg[k + 1];
                const float m = (c != PAD_I) ? 1.f : 0.f;
                cnt += (c != PAD_I) ? 1 : 0;
                if (s >= 1) {
                    const int p  = tg[k];
                    const int pw = (p < 0) ? p + TP2 : p;
                    const int cw = (c < 0) ? c + TP2 : c;
                    acc += trans[pw*TP2 + cw] * m;
                }
                if (s <= S_LEN - 2) {
                    int cc = c; if (cc < 0) cc = 0;
                    acc += em[((size_t)s*B_SZ + b)*T_TAGS + cc] * m;
                }
            }
            pl[q*B_SZ + b] = acc;
            pc[q*B_SZ + b] = cnt;
        }
    }

    // ---------------- common tail: last-done block finishes ----------------
    __threadfence();
    if (t == 0) {
        const unsigned old = atomicAdd(counter, 1u);
        lastflag = (old == TOT_BLOCKS - 1) ? 1 : 0;
    }
    __syncthreads();
    if (lastflag) {
        __threadfence();   // acquire: see all blocks' pl/pc/denom stores
        float part = 0.f;
        for (int b = t; b < B_SZ; b += NTHR) {
            float llh = 0.f;
            int cnt = 0;
            #pragma unroll
            for (int q = 0; q < NQ; ++q) {
                llh += pl[q*B_SZ + b];
                cnt += pc[q*B_SZ + b];
            }
            int li = cnt - 1; if (li < 0) li = 0;
            const int lt  = tags[li*B_SZ + b];
            const int ltw = (lt < 0) ? lt + TP2 : lt;
            llh += trans[ltw*TP2 + (T_TAGS + 1)];
            const float ml = (tags[(S_LEN - 1)*B_SZ + b] != PAD_I) ? 1.f : 0.f;
            int ltc = lt; if (ltc < 0) ltc = 0;
            llh += em[((size_t)(S_LEN - 1)*B_SZ + b)*T_TAGS + ltc] * ml;
            part += llh - denom_out[b];
        }
        #pragma unroll
        for (int off = 32; off; off >>= 1)
            part += __shfl_xor(part, off);
        float* red = &EE[0][0][0][0];
        if ((t & 63) == 0) red[t >> 6] = part;
        __syncthreads();
        if (t == 0)
            out[0] = (red[0] + red[1] + red[2]) * (1.f / (float)B_SZ);
    }
}

extern "C" void kernel_launch(void* const* d_in, const int* in_sizes, int n_in,
                              void* d_out, int out_size, void* d_ws, size_t ws_size,
                              hipStream_t stream) {
    const float* em    = (const float*)d_in[0];
    const float* trans = (const float*)d_in[1];
    const int*   tags  = (const int*)d_in[2];
    float* out   = (float*)d_out;

    float* denom = (float*)d_ws;                         // 512 f
    float* pl    = denom + B_SZ;                         // NQ*512 f
    int*   pc    = (int*)(pl + NQ*B_SZ);                 // NQ*512 i
    unsigned int* counter = (unsigned int*)(pc + NQ*B_SZ);

    hipMemsetAsync(counter, 0, sizeof(unsigned int), stream);
    crf_main<<<TOT_BLOCKS, NTHR, 0, stream>>>(em, trans, tags, denom, pl, pc, counter, out);
}